// Round 4
// baseline (166.927 us; speedup 1.0000x reference)
//
#include <hip/hip_runtime.h>
#include <stdint.h>

// out[n,o] = sum_{d,i} q[n,d] x[n,i] W1[d,i,o] + (q @ b1)[n,o]
// GEMM M=4096 N=256 K=16384 (k=d*256+i), fp16 MFMA 32x32x16, fp32 accum.
// A-frag = x-frag (LDS-resident) * q[row,d] per-lane scalar.
// R4: MBLK=128 (halves W re-reads: 264 MB total), W fragments loaded DIRECTLY
// into VGPRs (no LDS round-trip, register double-buffer, compiler waitcnt).
// SPLIT=16 -> grid 512, 2 blocks/CU (LDS = 64 KB x-tile only), 8 waves/CU.

typedef _Float16 f16;
typedef f16 f16x8 __attribute__((ext_vector_type(8)));
typedef float f32x16 __attribute__((ext_vector_type(16)));

#define NROWS 4096
#define QDIM 64
#define SPLIT 16
#define MBLK 128
#define MBCNT (NROWS / MBLK)  // 32
#define CHUNKS 32             // per sg: 4 d's x 8 ic

__device__ __forceinline__ void gl_lds16(const void* g, void* s) {
  __builtin_amdgcn_global_load_lds(
      (const __attribute__((address_space(1))) void*)(uintptr_t)g,
      (__attribute__((address_space(3))) void*)(uint32_t)(uintptr_t)s,
      16, 0, 0);
}

// Wt chunk g = sg*32 + ic*4 + dd  (d = sg*4+dd), chunk = 16 KB:
//   unit u = (s*2+h)*256 + n  holds  W1[(d*256 + ic*32 + s*16 + h*8 + j)*256 + n]
// prep grid 1152: [0,512) W cvt | [512,640) x cvt | [640,1152) bias-init out
__global__ __launch_bounds__(256) void prep(const float* __restrict__ W,
                                            const float* __restrict__ X,
                                            const float* __restrict__ Q,
                                            const float* __restrict__ B1,
                                            f16* __restrict__ Wt,
                                            f16* __restrict__ Xt,
                                            float* __restrict__ out) {
  __shared__ float qs[512];
  const int b = blockIdx.x;
  const int t = threadIdx.x;
  if (b < 512) {
    const int d = b >> 3, ic = b & 7;
    const int g = ((d >> 2) << 5) + (ic << 2) + (d & 3);
    const int k0 = d * 256 + (ic << 5);
#pragma unroll
    for (int r = 0; r < 4; ++r) {
      const int gidx = (r << 8) + t;  // (s*2+h)*256 + n
      const int n = gidx & 255;
      const int sh = gidx >> 8;
      f16x8 h;
#pragma unroll
      for (int j = 0; j < 8; ++j)
        h[j] = (f16)W[(size_t)(k0 + (sh << 3) + j) * 256 + n];  // coalesced over n
      *(f16x8*)(Wt + (size_t)g * 8192 + (size_t)gidx * 8) = h;
    }
  } else if (b < 640) {
    // Xt[mb][ (hsic*128 + row)*8 + j ] = x[mb*128+row][hsic*8+j]
    const int bb = b - 512;           // 0..127
    const int mb = bb >> 2, q4 = bb & 3;
#pragma unroll
    for (int r = 0; r < 4; ++r) {
      const int u = (q4 << 10) + (r << 8) + t;  // unit 0..4095
      const int row = u & 127;
      const int hsic = u >> 7;
      const float* src = X + (size_t)((mb << 7) + row) * 256 + (hsic << 3);
      float4 a = *(const float4*)src;
      float4 c = *(const float4*)(src + 4);
      f16x8 h;
      h[0] = (f16)a.x; h[1] = (f16)a.y; h[2] = (f16)a.z; h[3] = (f16)a.w;
      h[4] = (f16)c.x; h[5] = (f16)c.y; h[6] = (f16)c.z; h[7] = (f16)c.w;
      *(f16x8*)(Xt + (size_t)mb * 32768 + (size_t)u * 8) = h;
    }
  } else {
    // bias-init: out[n0+r][t] = sum_d q[n0+r][d] * b1[d][t]   (8 rows/block)
    const int n0 = (b - 640) << 3;
    qs[t] = Q[(size_t)n0 * QDIM + t];
    qs[256 + t] = Q[(size_t)n0 * QDIM + 256 + t];
    __syncthreads();
    float a8[8] = {0.f, 0.f, 0.f, 0.f, 0.f, 0.f, 0.f, 0.f};
#pragma unroll 4
    for (int d = 0; d < 64; ++d) {
      const float bv = B1[d * 256 + t];
#pragma unroll
      for (int r = 0; r < 8; ++r) a8[r] += qs[(r << 6) + d] * bv;
    }
#pragma unroll
    for (int r = 0; r < 8; ++r) out[(size_t)(n0 + r) * 256 + t] = a8[r];
  }
}

// ---- main GEMM: 512 blocks = 16 split groups x 32 row-blocks ----
// sg = bid&15: under round-robin bid->XCD, XCD x hosts sgs {x, x+8}:
// W working set 2 x 512 KB per XCD -> L2-resident.
__global__ __launch_bounds__(256, 2) void mlp_main(const float* __restrict__ Q,
                                                   const f16* __restrict__ Wt,
                                                   const f16* __restrict__ Xt,
                                                   float* __restrict__ out) {
  __shared__ f16 s_x[32768];  // 64 KB x tile (128 rows x 256 k-slice)

  const int bid = blockIdx.x;
  const int sg = bid & 15;
  const int mb = bid >> 4;
  const int t = threadIdx.x;
  const int w = t >> 6;
  const int l = t & 63;
  const int l31 = l & 31;
  const int hf = l >> 5;

  // stage x tile (64 KB) cooperatively, async
  const char* xg = (const char*)(Xt + (size_t)mb * 32768);
  char* xs = (char*)s_x;
#pragma unroll
  for (int i = 0; i < 16; ++i) {
    const int off = (((w << 4) + i) << 10) + (l << 4);
    gl_lds16(xg + off, xs + off);
  }

  // W fragment pointers (f16x8 units). frag(s,nt) unit = (s*2+hf)*256 + w*64 + nt*32 + l31
  const f16x8* wgp = (const f16x8*)(Wt + (size_t)sg * CHUNKS * 8192);
  const int fb = (hf << 8) + (w << 6) + l31;  // + s*512 + nt*32 ; chunk stride 1024 units

  // per-lane q scalars: q[mb*128 + mt*32 + l31][sg*4 + dd]
  f16 qr[4][4];
#pragma unroll
  for (int mt = 0; mt < 4; ++mt) {
    float4 qv = *(const float4*)(Q + (size_t)((mb << 7) + (mt << 5) + l31) * QDIM + (sg << 2));
    qr[mt][0] = (f16)qv.x; qr[mt][1] = (f16)qv.y;
    qr[mt][2] = (f16)qv.z; qr[mt][3] = (f16)qv.w;
  }

  f32x16 acc[4][2];
#pragma unroll
  for (int a = 0; a < 4; ++a)
#pragma unroll
    for (int bq = 0; bq < 2; ++bq)
#pragma unroll
      for (int r = 0; r < 16; ++r) acc[a][bq][r] = 0.f;

  // preload chunk 0 W frags into registers
  f16x8 wreg[2][4];
#pragma unroll
  for (int s = 0; s < 2; ++s)
#pragma unroll
    for (int nt = 0; nt < 2; ++nt)
      wreg[0][(s << 1) + nt] = wgp[fb + (s << 9) + (nt << 5)];

  __syncthreads();  // x tile (and preload) visible

  for (int ic = 0; ic < 8; ++ic) {
    f16x8 xf[4][2];  // x-frags reused across 4 d-iterations
#pragma unroll
    for (int mt = 0; mt < 4; ++mt)
#pragma unroll
      for (int s = 0; s < 2; ++s)
        xf[mt][s] = *(const f16x8*)(s_x +
            ((((ic << 2) + (s << 1) + hf) << 7) + (mt << 5) + l31) * 8);
#pragma unroll
    for (int dd = 0; dd < 4; ++dd) {
      const int c = (ic << 2) + dd;
      const int nc = (c + 1) & 31;  // wrap: harmless redundant load on last iter
      f16x8* wn = wreg[(c + 1) & 1];
      const f16x8* wc = wreg[c & 1];
      // issue next chunk's 4 fragment loads (register double buffer)
#pragma unroll
      for (int s = 0; s < 2; ++s)
#pragma unroll
        for (int nt = 0; nt < 2; ++nt)
          wn[(s << 1) + nt] = wgp[(size_t)nc * 1024 + fb + (s << 9) + (nt << 5)];
      // compute, one k=16 step (s) at a time to limit live a-frags
#pragma unroll
      for (int s = 0; s < 2; ++s) {
        f16x8 a0 = xf[0][s] * qr[0][dd];
        f16x8 a1 = xf[1][s] * qr[1][dd];
        f16x8 a2 = xf[2][s] * qr[2][dd];
        f16x8 a3 = xf[3][s] * qr[3][dd];
        const f16x8 b0 = wc[(s << 1) + 0];
        const f16x8 b1f = wc[(s << 1) + 1];
        acc[0][0] = __builtin_amdgcn_mfma_f32_32x32x16_f16(a0, b0, acc[0][0], 0, 0, 0);
        acc[1][0] = __builtin_amdgcn_mfma_f32_32x32x16_f16(a1, b0, acc[1][0], 0, 0, 0);
        acc[2][0] = __builtin_amdgcn_mfma_f32_32x32x16_f16(a2, b0, acc[2][0], 0, 0, 0);
        acc[3][0] = __builtin_amdgcn_mfma_f32_32x32x16_f16(a3, b0, acc[3][0], 0, 0, 0);
        acc[0][1] = __builtin_amdgcn_mfma_f32_32x32x16_f16(a0, b1f, acc[0][1], 0, 0, 0);
        acc[1][1] = __builtin_amdgcn_mfma_f32_32x32x16_f16(a1, b1f, acc[1][1], 0, 0, 0);
        acc[2][1] = __builtin_amdgcn_mfma_f32_32x32x16_f16(a2, b1f, acc[2][1], 0, 0, 0);
        acc[3][1] = __builtin_amdgcn_mfma_f32_32x32x16_f16(a3, b1f, acc[3][1], 0, 0, 0);
      }
    }
  }

  // epilogue: atomic split-K accumulate onto bias-initialized out.
  // C/D (32x32): col = lane&31, row = (reg&3) + 8*(reg>>2) + 4*(lane>>5)
#pragma unroll
  for (int mt = 0; mt < 4; ++mt) {
#pragma unroll
    for (int nt = 0; nt < 2; ++nt) {
#pragma unroll
      for (int r = 0; r < 16; ++r) {
        const int row = (mb << 7) + (mt << 5) + (r & 3) + ((r >> 2) << 3) + (hf << 2);
        const int col = (w << 6) + (nt << 5) + l31;
        atomicAdd(out + (size_t)row * 256 + col, acc[mt][nt][r]);
      }
    }
  }
}

extern "C" void kernel_launch(void* const* d_in, const int* in_sizes, int n_in,
                              void* d_out, int out_size, void* d_ws, size_t ws_size,
                              hipStream_t stream) {
  (void)in_sizes; (void)n_in; (void)out_size; (void)ws_size;
  const float* x  = (const float*)d_in[0];   // [4096,256]
  const float* q  = (const float*)d_in[1];   // [4096,64]
  const float* W1 = (const float*)d_in[2];   // [64,256,256]
  const float* b1 = (const float*)d_in[3];   // [64,256]
  float* out = (float*)d_out;                // [4096,256] fp32

  // ws: Wt 512 chunks x 16 KB = 8 MB | Xt 2 MB   (~10 MB total)
  f16* Wt = (f16*)d_ws;
  f16* Xt = (f16*)((char*)d_ws + (size_t)512 * 16384);

  prep<<<1152, 256, 0, stream>>>(W1, x, q, b1, Wt, Xt, out);
  mlp_main<<<MBCNT * SPLIT, 256, 0, stream>>>(q, Wt, Xt, out);
}